// Round 6
// baseline (297.388 us; speedup 1.0000x reference)
//
#include <hip/hip_runtime.h>
#include <hip/hip_bf16.h>
#include <stdint.h>

typedef __hip_bfloat16 bf16;
typedef __attribute__((ext_vector_type(8))) short short8;   // 8 x bf16 = 16B
typedef __attribute__((ext_vector_type(4))) float float4v;

#define MFMA16(a, b, c) __builtin_amdgcn_mfma_f32_16x16x32_bf16((a), (b), (c), 0, 0, 0)

static __device__ __forceinline__ short f2bf(float f) {
    bf16 h = __float2bfloat16(f);
    return *reinterpret_cast<short*>(&h);
}

// async global->LDS, 16B per lane; dest = lds_base + lane*16 (wave-uniform base)
static __device__ __forceinline__ void gl2lds16(const void* g, void* l) {
    __builtin_amdgcn_global_load_lds(
        (const __attribute__((address_space(1))) void*)g,
        (__attribute__((address_space(3))) void*)l, 16, 0, 0);
}

// =====================================================================
// f32 -> bf16 elementwise convert (n multiple of 8)
// =====================================================================
__global__ __launch_bounds__(256) void cvt_f32_bf16(
    const float* __restrict__ in, bf16* __restrict__ out, int n)
{
    const int i = (blockIdx.x * 256 + threadIdx.x) * 8;
    if (i < n) {
        const float4v a = *(const float4v*)(in + i);
        const float4v b = *(const float4v*)(in + i + 4);
        short8 v;
#pragma unroll
        for (int q = 0; q < 4; ++q) { v[q] = f2bf(a[q]); v[q + 4] = f2bf(b[q]); }
        *(short8*)(out + i) = v;
    }
}

// =====================================================================
// GEMM: C[M][N] = X[M][K] @ W[N][K]^T + bias[N]; X,W bf16, bias f32.
// mode 0: store C f32 to Cout; if gridDim.z>1, split-K with atomicAdd
//         (Cout must be pre-zeroed; bias added only by z==0 blocks).
// mode 1: QKV scatter: col<2304 -> QK bf16 row-major; col>=2304 -> Vt bf16
//         transposed [h][d][tok].
// 128x128 tile, BK=32, 4 waves (2x2 of 64x64), 16x16x32 bf16 MFMA.
// DOUBLE-BUFFERED LDS: one barrier per K-iter; next tile's
// global_load_lds issues stay in flight across the whole compute phase.
// 16B-chunk XOR swizzle on the global source keeps fragment ds_read_b128
// bank-optimal (verified 0 conflicts in R5).
// =====================================================================
__global__ __launch_bounds__(256) void gemm_xwt(
    const bf16* __restrict__ X, const bf16* __restrict__ W,
    const float* __restrict__ bias,
    float* __restrict__ Cout,
    bf16* __restrict__ QK, bf16* __restrict__ Vt,
    int M, int N, int K, int mode)
{
    __shared__ __align__(16) bf16 As[2][128 * 32];
    __shared__ __align__(16) bf16 Bs[2][128 * 32];

    const int tid  = threadIdx.x;
    const int wave = tid >> 6;
    const int lane = tid & 63;
    const int quad = lane >> 4;
    const int l16  = lane & 15;
    const int m0 = blockIdx.x * 128;
    const int n0 = blockIdx.y * 128;
    const int wm = (wave >> 1) * 64;
    const int wn = (wave & 1) * 64;

    const int lrow   = lane >> 2;   // 0..15
    const int lchunk = lane & 3;    // 16B chunk within a 64B row

    const int kper = K / gridDim.z;
    const int kbeg = blockIdx.z * kper;
    const int nIt  = kper >> 5;

    float4v acc[4][4];
    const float4v zf = {0.f, 0.f, 0.f, 0.f};
#pragma unroll
    for (int i = 0; i < 4; ++i)
#pragma unroll
        for (int j = 0; j < 4; ++j) acc[i][j] = zf;

    // stage tile (k0) into buffer `buf`
    auto stage = [&](int buf, int k0) {
#pragma unroll
        for (int ii = 0; ii < 2; ++ii) {
            const int rbase = wave * 32 + ii * 16;
            const int r  = rbase + lrow;
            const int sc = lchunk ^ ((r >> 1) & 3);
            gl2lds16(&X[(size_t)(m0 + r) * K + k0 + sc * 8], &As[buf][rbase * 32]);
            gl2lds16(&W[(size_t)(n0 + r) * K + k0 + sc * 8], &Bs[buf][rbase * 32]);
        }
    };

    stage(0, kbeg);   // prologue

    for (int it = 0; it < nIt; ++it) {
        __syncthreads();   // drains cur-buffer loads; guards next-buffer reuse
        if (it + 1 < nIt) stage((it + 1) & 1, kbeg + (it + 1) * 32);

        const int b = it & 1;
        short8 af[4], bfr[4];
#pragma unroll
        for (int i = 0; i < 4; ++i) {
            const int r = wm + i * 16 + l16;
            af[i] = *(const short8*)&As[b][r * 32 + (quad ^ ((r >> 1) & 3)) * 8];
        }
#pragma unroll
        for (int j = 0; j < 4; ++j) {
            const int r = wn + j * 16 + l16;
            bfr[j] = *(const short8*)&Bs[b][r * 32 + (quad ^ ((r >> 1) & 3)) * 8];
        }
#pragma unroll
        for (int i = 0; i < 4; ++i)
#pragma unroll
            for (int j = 0; j < 4; ++j)
                acc[i][j] = MFMA16(af[i], bfr[j], acc[i][j]);
    }

    // epilogue: C/D layout col=lane&15, row=quad*4+reg
    const bool split = (gridDim.z > 1);
    const float bscale = (!split || blockIdx.z == 0) ? 1.f : 0.f;
#pragma unroll
    for (int j = 0; j < 4; ++j) {
        const int col = n0 + wn + j * 16 + l16;
        const float bb = bias[col] * bscale;
#pragma unroll
        for (int i = 0; i < 4; ++i) {
#pragma unroll
            for (int r = 0; r < 4; ++r) {
                const int row = m0 + wm + i * 16 + quad * 4 + r;
                const float val = acc[i][j][r] + bb;
                if (mode == 0) {
                    if (split) atomicAdd(&Cout[(size_t)row * N + col], val);
                    else       Cout[(size_t)row * N + col] = val;
                } else {
                    const bf16 bv = __float2bfloat16(val);
                    if (col < 2304) {
                        QK[(size_t)row * 2304 + col] = bv;
                    } else {
                        const int c2 = col - 2304;
                        const int hh = c2 / 72;
                        const int dd = c2 - hh * 72;
                        Vt[((size_t)hh * 72 + dd) * 4096 + row] = bv;
                    }
                }
            }
        }
    }
}

// =====================================================================
// Varlen flash attention, staging-free Q/K:
//  - Q and K MFMA fragments loaded directly global->VGPR (per-lane 16B;
//    fragment row = lane&15 matches the 16x16x32 A/B layout).
//  - kv tiles aligned to 64 (mask kv<seq_start too): all V staging is
//    16B-aligned ds_write_b128, no clamps, no OOB.
//  - Only V round-trips LDS; P round-trip is per-wave (no barrier).
//  - 2 barriers per kv tile (was 3), LDS 20 KB (was 40).
// Grid: (qblock<=72, head=16). Block 256 = 4 waves.
// =====================================================================
__global__ __launch_bounds__(256) void attn_varlen(
    const bf16* __restrict__ QK, const bf16* __restrict__ Vt,
    const int* __restrict__ cu, bf16* __restrict__ AO)
{
    const float scale = 0.11785113019775793f;  // 72^-0.5
    __shared__ __align__(16) bf16 Vs[72 * 72];      // [dim][tok], stride 72
    __shared__ __align__(16) bf16 Ps[4][16 * 72];   // per-wave P, stride 72

    const int tid  = threadIdx.x;
    const int wave = tid >> 6;
    const int lane = tid & 63;
    const int quad = lane >> 4;
    const int l16  = lane & 15;
    const int h  = blockIdx.y;
    const int qb = blockIdx.x;

    int seq_end = 0, q0 = -1, accb = 0, seq_start = 0;
    for (int i = 0; i < 8; ++i) {
        const int st = cu[i], en = cu[i + 1];
        const int nb = (en - st + 63) >> 6;
        if (q0 < 0 && qb < accb + nb) {
            seq_start = st; seq_end = en; q0 = st + (qb - accb) * 64;
        }
        accb += nb;
    }
    if (q0 < 0) return;

    const short8 z8 = {0, 0, 0, 0, 0, 0, 0, 0};

    // Q fragments, direct from global (rows clamped: tail q-blocks may
    // reach past 4095; outputs for those rows are discarded anyway)
    int qrow_f = q0 + wave * 16 + l16; if (qrow_f > 4095) qrow_f = 4095;
    const bf16* qp = &QK[(size_t)qrow_f * 2304 + h * 72];
    short8 aq[3];
    aq[0] = *(const short8*)(qp + quad * 8);
    aq[1] = *(const short8*)(qp + 32 + quad * 8);
    aq[2] = (quad == 0) ? *(const short8*)(qp + 64) : z8;  // dims 64..71, rest 0

    const float4v zf = {0.f, 0.f, 0.f, 0.f};
    float4v oacc[5];
#pragma unroll
    for (int d = 0; d < 5; ++d) oacc[d] = zf;
    float m_i[4], l_i[4];
#pragma unroll
    for (int r = 0; r < 4; ++r) { m_i[r] = -1.0e30f; l_i[r] = 0.f; }

    const int kvbeg = seq_start & ~63;
    for (int kv0 = kvbeg; kv0 < seq_end; kv0 += 64) {
        __syncthreads();   // Vs reuse guard (prior PV reads done)
        // stage V^T tile [72][64], all b128, 16B aligned (kv0 % 64 == 0)
        for (int c = tid; c < 72 * 8; c += 256) {
            const int d = c >> 3, cc = c & 7;
            *(short8*)&Vs[d * 72 + cc * 8] =
                *(const short8*)&Vt[((size_t)(h * 72 + d)) * 4096 + kv0 + cc * 8];
        }
        // K fragments, direct from global (issue before barrier; in flight
        // during the barrier wait)
        short8 bk[4][3];
#pragma unroll
        for (int nt = 0; nt < 4; ++nt) {
            const bf16* kp = &QK[(size_t)(kv0 + nt * 16 + l16) * 2304 + 1152 + h * 72];
            bk[nt][0] = *(const short8*)(kp + quad * 8);
            bk[nt][1] = *(const short8*)(kp + 32 + quad * 8);
            bk[nt][2] = (quad == 0) ? *(const short8*)(kp + 64) : z8;
        }
        __syncthreads();   // Vs ready

        float4v sc[4];
#pragma unroll
        for (int nt = 0; nt < 4; ++nt) {
            float4v s = zf;
#pragma unroll
            for (int kk = 0; kk < 3; ++kk)
                s = MFMA16(aq[kk], bk[nt][kk], s);
            sc[nt] = s;
        }
        // mask (both ends: aligned grid can underrun seq_start) + scale
#pragma unroll
        for (int nt = 0; nt < 4; ++nt) {
            const int kv = kv0 + nt * 16 + l16;
            const bool ok = (kv >= seq_start) && (kv < seq_end);
#pragma unroll
            for (int r = 0; r < 4; ++r)
                sc[nt][r] = ok ? sc[nt][r] * scale : -1.0e30f;
        }
        // online softmax: rows at quad*4+reg, cols across the 16-lane group
        float mnew[4], alpha[4];
#pragma unroll
        for (int r = 0; r < 4; ++r) {
            float rm = fmaxf(fmaxf(sc[0][r], sc[1][r]), fmaxf(sc[2][r], sc[3][r]));
            rm = fmaxf(rm, __shfl_xor(rm, 1));
            rm = fmaxf(rm, __shfl_xor(rm, 2));
            rm = fmaxf(rm, __shfl_xor(rm, 4));
            rm = fmaxf(rm, __shfl_xor(rm, 8));
            mnew[r]  = fmaxf(m_i[r], rm);
            alpha[r] = __expf(m_i[r] - mnew[r]);
            m_i[r]   = mnew[r];
        }
        float rs[4] = {0.f, 0.f, 0.f, 0.f};
#pragma unroll
        for (int nt = 0; nt < 4; ++nt)
#pragma unroll
            for (int r = 0; r < 4; ++r) {
                const float p = __expf(sc[nt][r] - mnew[r]);
                sc[nt][r] = p;
                rs[r] += p;
            }
#pragma unroll
        for (int r = 0; r < 4; ++r) {
            rs[r] += __shfl_xor(rs[r], 1);
            rs[r] += __shfl_xor(rs[r], 2);
            rs[r] += __shfl_xor(rs[r], 4);
            rs[r] += __shfl_xor(rs[r], 8);
            l_i[r] = l_i[r] * alpha[r] + rs[r];
        }
#pragma unroll
        for (int d = 0; d < 5; ++d)
#pragma unroll
            for (int r = 0; r < 4; ++r) oacc[d][r] *= alpha[r];

        // P (C-layout) -> per-wave LDS -> A-layout. No barrier needed:
        // Ps[wave] is wave-private; compiler inserts the lgkmcnt wait.
#pragma unroll
        for (int nt = 0; nt < 4; ++nt)
#pragma unroll
            for (int r = 0; r < 4; ++r)
                Ps[wave][(quad * 4 + r) * 72 + nt * 16 + l16] = __float2bfloat16(sc[nt][r]);

        const short8 ap0 = *(const short8*)&Ps[wave][l16 * 72 + quad * 8];
        const short8 ap1 = *(const short8*)&Ps[wave][l16 * 72 + 32 + quad * 8];
#pragma unroll
        for (int d = 0; d < 5; ++d) {
            short8 bv0 = *(const short8*)&Vs[(d * 16 + l16) * 72 + quad * 8];
            short8 bv1 = *(const short8*)&Vs[(d * 16 + l16) * 72 + 32 + quad * 8];
            oacc[d] = MFMA16(ap0, bv0, oacc[d]);
            oacc[d] = MFMA16(ap1, bv1, oacc[d]);
        }
    }

    // epilogue: AO[t][h*72+d] = O / l
#pragma unroll
    for (int r = 0; r < 4; ++r) {
        const int qrow = q0 + wave * 16 + quad * 4 + r;
        if (qrow < seq_end) {
            const float inv = (l_i[r] > 0.f) ? (1.0f / l_i[r]) : 0.f;
#pragma unroll
            for (int d = 0; d < 5; ++d) {
                const int dim = d * 16 + l16;
                if (dim < 72)
                    AO[(size_t)qrow * 1152 + h * 72 + dim] =
                        __float2bfloat16(oacc[d][r] * inv);
            }
        }
    }
}

extern "C" void kernel_launch(void* const* d_in, const int* in_sizes, int n_in,
                              void* d_out, int out_size, void* d_ws, size_t ws_size,
                              hipStream_t stream)
{
    const float* Xf   = (const float*)d_in[0];  // [4096][1152]
    const float* Wqkv = (const float*)d_in[1];  // [3456][1152]
    const float* Bqkv = (const float*)d_in[2];  // [3456]
    const float* Wout = (const float*)d_in[3];  // [1152][1152]
    const float* Bout = (const float*)d_in[4];  // [1152]
    const int*   cu   = (const int*)d_in[5];    // [9]

    const size_t X16_B  = (size_t)4096 * 1152 * 2;
    const size_t WQ16_B = (size_t)3456 * 1152 * 2;
    const size_t WO16_B = (size_t)1152 * 1152 * 2;
    const size_t QK_B   = (size_t)4096 * 2304 * 2;
    const size_t VT_B   = (size_t)16 * 72 * 4096 * 2;

    char* ws = (char*)d_ws;
    bf16* X16  = (bf16*)ws;
    bf16* WQ16 = (bf16*)(ws + X16_B);
    bf16* WO16 = (bf16*)(ws + X16_B + WQ16_B);
    bf16* QK   = (bf16*)(ws + X16_B + WQ16_B + WO16_B);
    bf16* Vt   = (bf16*)(ws + X16_B + WQ16_B + WO16_B + QK_B);
    bf16* AO   = (bf16*)(ws + X16_B + WQ16_B + WO16_B + QK_B + VT_B);
    float* Out = (float*)d_out;

    dim3 blk(256);
    // f32 -> bf16 one-shot conversions
    cvt_f32_bf16<<<dim3(4096 * 1152 / 8 / 256), blk, 0, stream>>>(Xf, X16, 4096 * 1152);
    cvt_f32_bf16<<<dim3(3456 * 1152 / 8 / 256), blk, 0, stream>>>(Wqkv, WQ16, 3456 * 1152);
    cvt_f32_bf16<<<dim3(1152 * 1152 / 8 / 256), blk, 0, stream>>>(Wout, WO16, 1152 * 1152);

    // zero d_out for split-K atomics
    hipMemsetAsync(d_out, 0, (size_t)4096 * 1152 * 4, stream);

    // QKV projection (scatter Q,K row-major bf16 + V transposed), full K
    gemm_xwt<<<dim3(32, 27, 1), blk, 0, stream>>>(X16, WQ16, Bqkv, nullptr, QK, Vt,
                                                  4096, 3456, 1152, 1);
    // varlen attention
    attn_varlen<<<dim3(72, 16), blk, 0, stream>>>(QK, Vt, cu, AO);
    // output projection, split-K=2 (576 blocks), f32 atomic accumulate
    gemm_xwt<<<dim3(32, 9, 2), blk, 0, stream>>>(AO, WO16, Bout, Out, nullptr, nullptr,
                                                 4096, 1152, 1152, 0);
}